// Round 10
// baseline (356.418 us; speedup 1.0000x reference)
//
#include <hip/hip_runtime.h>
#include <stdint.h>

#define B_ 4
#define H_ 16
#define NQ_ 1024
#define NK_ 1024
#define DM_ 1024
#define DK_ 64

typedef __attribute__((ext_vector_type(8))) short short8;
typedef __attribute__((ext_vector_type(4))) float f32x4;
typedef unsigned short u16;
typedef unsigned int u32;

__device__ __forceinline__ u16 f2bf(float f) {
  u32 u = __builtin_bit_cast(u32, f);
  u32 r = u + 0x7fffu + ((u >> 16) & 1u);
  return (u16)(r >> 16);
}

__device__ __forceinline__ float bf2f(u16 b) {
  u32 u = ((u32)b) << 16;
  return __builtin_bit_cast(float, u);
}

__device__ __forceinline__ short8 ld_short8(const u16* p) {
  return __builtin_bit_cast(short8, *(const int4*)p);
}

// ---- asm load primitives ----
__device__ __forceinline__ int4 gload16(const void* p) {
  int4 d;
  asm volatile("global_load_dwordx4 %0, %1, off" : "=v"(d) : "v"(p));
  return d;
}
__device__ __forceinline__ int2 gload8(const void* p) {
  int2 d;
  asm volatile("global_load_dwordx2 %0, %1, off" : "=v"(d) : "v"(p));
  return d;
}
#define VMW(N) do { asm volatile("s_waitcnt vmcnt(" #N ")" ::: "memory"); \
                    __builtin_amdgcn_sched_barrier(0); } while (0)
#define LGKM_BARRIER() do { \
    asm volatile("s_waitcnt lgkmcnt(0)\n\ts_barrier" ::: "memory"); \
    __builtin_amdgcn_sched_barrier(0); } while (0)

// direct global->LDS (16B per lane); dest must be wave-uniform + lane*16
typedef const __attribute__((address_space(1))) unsigned int* as1_t;
typedef __attribute__((address_space(3))) unsigned int* as3_t;
__device__ __forceinline__ void gload_lds16(const u16* g, u16* l) {
  __builtin_amdgcn_global_load_lds((as1_t)(const void*)g, (as3_t)(void*)l, 16, 0, 0);
}

// ---------------------------------------------------------------------------
// Mask storage detector: bool (1 byte/elem) vs int32 (4 bytes/elem).
// ---------------------------------------------------------------------------
__global__ void detect_mask_kernel(const unsigned char* __restrict__ m, int* __restrict__ flag) {
  if (threadIdx.x == 0) {
    int f = 0;
    for (int i = 0; i < 256; ++i)
      if ((i & 3) != 0 && m[i] != 0) f = 1;
    *flag = f;  // 1 => byte mask, 0 => int32 mask
  }
}

// ---------------------------------------------------------------------------
// fp32 -> bf16 streaming convert (q/k/v into scratch carved from d_out's att
// region; consumed by the QKV GEMM before attn overwrites it).
// ---------------------------------------------------------------------------
__global__ __launch_bounds__(256) void convert_kernel(
    const float* __restrict__ q, const float* __restrict__ k, const float* __restrict__ v,
    u16* __restrict__ dst)
{
  const int y = blockIdx.y;  // 0..2
  const float* src = (y == 0) ? q : (y == 1 ? k : v);
  u16* d = dst + (size_t)y * 4194304;
  const size_t nchunk = 4194304 / 8;
  const size_t stride = (size_t)gridDim.x * 256;
  for (size_t i = (size_t)blockIdx.x * 256 + threadIdx.x; i < nchunk; i += stride) {
    const float4 f0 = *(const float4*)(src + i * 8);
    const float4 f1 = *(const float4*)(src + i * 8 + 4);
    short8 p;
    p[0] = (short)f2bf(f0.x); p[1] = (short)f2bf(f0.y);
    p[2] = (short)f2bf(f0.z); p[3] = (short)f2bf(f0.w);
    p[4] = (short)f2bf(f1.x); p[5] = (short)f2bf(f1.y);
    p[6] = (short)f2bf(f1.z); p[7] = (short)f2bf(f1.w);
    *(int4*)(d + i * 8) = __builtin_bit_cast(int4, p);
  }
}

// ---------------------------------------------------------------------------
// GEMM v2 (m97-style): C[m][n] = sum_k A[m][k]*W[n][k] + bias[n]
// A: bf16 (pre-converted / obuf), staged via global_load_lds(16B) into
// [128][64] bf16 LDS with XOR swizzle (byte ^= (row&7)<<4) applied by
// PRE-SWIZZLING the global source (LDS dest stays linear, m173).
// W: fp32, reg-staged + converted, ds_write to the same swizzled layout.
// BK=64, 2 barriers/K-tile (16 tiles), 32 MFMA/wave/tile.
// ---------------------------------------------------------------------------
__global__ __launch_bounds__(256) void gemm_kernel(
    const u16* __restrict__ Aq, const u16* __restrict__ Ak, const u16* __restrict__ Av,
    const u16* __restrict__ Ao,
    const float* __restrict__ Wq, const float* __restrict__ Wk,
    const float* __restrict__ Wv, const float* __restrict__ Wo,
    const float* __restrict__ bq, const float* __restrict__ bk,
    const float* __restrict__ bv, const float* __restrict__ bo,
    u16* __restrict__ qbuf, u16* __restrict__ kbuf, u16* __restrict__ vTbuf,
    float* __restrict__ outbuf, int mode_base)
{
  const int z = mode_base + (int)blockIdx.z;
  const int n0 = blockIdx.x * 128;
  const int m0 = blockIdx.y * 128;
  const int tid = threadIdx.x;
  const int lane = tid & 63;
  const int wave = tid >> 6;
  const int wm = wave >> 1, wn = wave & 1;
  const int l15 = lane & 15;
  const int hi = lane >> 4;

  __shared__ __attribute__((aligned(16))) u16 Al[128 * 64];
  __shared__ __attribute__((aligned(16))) u16 Bl[128 * 64];

  const u16* A = (z == 0) ? Aq : (z == 1 ? Ak : (z == 2 ? Av : Ao));
  const float* W = (z == 0) ? Wq : (z == 1 ? Wk : (z == 2 ? Wv : Wo));

  f32x4 acc[4][4];
#pragma unroll
  for (int i = 0; i < 4; ++i)
#pragma unroll
    for (int j = 0; j < 4; ++j) acc[i][j] = (f32x4){0.f, 0.f, 0.f, 0.f};

  for (int ks = 0; ks < 16; ++ks) {
    __syncthreads();   // prior compute done before overwrite
    // ---- A: 4x global_load_lds, source pre-swizzled ----
#pragma unroll
    for (int c = 0; c < 4; ++c) {
      const int p = c * 256 + tid;          // 16B chunk id 0..1023
      const int row = p >> 3;               // 0..127
      const int kbyte = ((p & 7) << 4) ^ ((row & 7) << 4);
      const u16* src = A + (size_t)(m0 + row) * DM_ + ks * 64 + (kbyte >> 1);
      gload_lds16(src, Al + p * 8);
    }
    // ---- B: reg-stage fp32 -> bf16, ds_write at swizzled address ----
#pragma unroll
    for (int c = 0; c < 4; ++c) {
      const int p = c * 256 + tid;
      const int row = p >> 3;
      const float* wsrc = W + (size_t)(n0 + row) * DM_ + ks * 64 + (p & 7) * 8;
      const float4 f0 = *(const float4*)(wsrc);
      const float4 f1 = *(const float4*)(wsrc + 4);
      short8 pk;
      pk[0] = (short)f2bf(f0.x); pk[1] = (short)f2bf(f0.y);
      pk[2] = (short)f2bf(f0.z); pk[3] = (short)f2bf(f0.w);
      pk[4] = (short)f2bf(f1.x); pk[5] = (short)f2bf(f1.y);
      pk[6] = (short)f2bf(f1.z); pk[7] = (short)f2bf(f1.w);
      const int cb = (((p & 7) << 4)) ^ ((row & 7) << 4);
      *(int4*)((char*)Bl + row * 128 + cb) = __builtin_bit_cast(int4, pk);
    }
    __syncthreads();   // implicit vmcnt(0)+lgkmcnt(0) drain: tiles ready
    // ---- compute: 2 x (8 ds_read_b128 + 16 MFMA) ----
#pragma unroll
    for (int kk = 0; kk < 2; ++kk) {
      short8 afr[4], bfr[4];
#pragma unroll
      for (int i = 0; i < 4; ++i) {
        const int ar = wm * 64 + i * 16 + l15;
        const int ab = (kk * 64 + hi * 16) ^ ((ar & 7) << 4);
        afr[i] = ld_short8(Al + ar * 64 + (ab >> 1));
        const int br = wn * 64 + i * 16 + l15;
        const int bb = (kk * 64 + hi * 16) ^ ((br & 7) << 4);
        bfr[i] = ld_short8(Bl + br * 64 + (bb >> 1));
      }
#pragma unroll
      for (int i = 0; i < 4; ++i)
#pragma unroll
        for (int j = 0; j < 4; ++j)
          acc[i][j] = __builtin_amdgcn_mfma_f32_16x16x32_bf16(afr[i], bfr[j], acc[i][j], 0, 0, 0);
    }
  }

  // epilogue (unchanged). D layout: col = lane&15, row = (lane>>4)*4 + r
  const float* bias = (z == 0) ? bq : (z == 1 ? bk : (z == 2 ? bv : bo));
#pragma unroll
  for (int i = 0; i < 4; ++i) {
    const int token0 = m0 + wm * 64 + i * 16 + hi * 4;
#pragma unroll
    for (int j = 0; j < 4; ++j) {
      const int feat = n0 + wn * 64 + j * 16 + l15;
      const float bvl = bias[feat];
      if (z == 3) {
#pragma unroll
        for (int r = 0; r < 4; ++r)
          outbuf[(size_t)(token0 + r) * DM_ + feat] = acc[i][j][r] + bvl;
      } else if (z == 2) {
        const int bb = token0 >> 10, t = token0 & 1023;
        const int hh = feat >> 6, d = feat & 63;
        ushort4 p;
        p.x = f2bf(acc[i][j][0] + bvl);
        p.y = f2bf(acc[i][j][1] + bvl);
        p.z = f2bf(acc[i][j][2] + bvl);
        p.w = f2bf(acc[i][j][3] + bvl);
        *(ushort4*)(vTbuf + ((size_t)(bb * H_ + hh) * DK_ + d) * NK_ + t) = p;
      } else {
        u16* dst = (z == 0) ? qbuf : kbuf;
        const int hh = feat >> 6, d = feat & 63;
#pragma unroll
        for (int r = 0; r < 4; ++r) {
          const int token = token0 + r;
          const int bb = token >> 10, t = token & 1023;
          dst[((size_t)(bb * H_ + hh) * NQ_ + t) * DK_ + d] = f2bf(acc[i][j][r] + bvl);
        }
      }
    }
  }
}

// ---------------------------------------------------------------------------
// Attention v9 (unchanged from R9 — best known: ~256 us).
// ---------------------------------------------------------------------------
__global__ __launch_bounds__(512) void attn_kernel(
    const u16* __restrict__ qbuf, const u16* __restrict__ kbuf, const u16* __restrict__ vTbuf,
    const float* __restrict__ aw, const void* __restrict__ maskp, const int* __restrict__ flagp,
    float* __restrict__ attout, u16* __restrict__ obuf)
{
  __shared__ u16 S[16 * 1024];  // 32 KB bf16 strip, col swizzle: c ^ ((row&7)<<3)

  const int n = blockIdx.x;
  const int work = (n & 7) * 512 + (n >> 3);  // XCD-chunked swizzle (perf only)
  const int qt = work & 63;
  const int bh = work >> 6;
  const int b = bh >> 4, h = bh & 15;
  const int qbase = qt * 16;
  const int tid = threadIdx.x;
  const int lane = tid & 63;
  const int wave = tid >> 6;   // 0..7
  const int hi = lane >> 4;
  const int l15 = lane & 15;
  const int mflag = *flagp;

  const int c0 = lane * 8;
  const size_t ab0 = ((size_t)bh * NQ_ + qbase + wave) * (size_t)NK_;
  const size_t ab1 = ab0 + 8 * (size_t)NK_;

  // ---- pre-QK issue: Q(2), K(16), aw row0(4) -- FIFO order is the contract
  const u16* qp = qbuf + ((size_t)bh * NQ_ + qbase + l15) * DK_ + hi * 8;
  int4 qd0 = gload16(qp);
  int4 qd1 = gload16(qp + 32);

  const u16* kbase = kbuf + (size_t)bh * NK_ * DK_;
  const int tkc = wave * 16 + l15;
  int4 kq0[8], kq1[8];
#pragma unroll
  for (int t = 0; t < 8; ++t) {
    const u16* kp_ = kbase + (size_t)(t * 128 + tkc) * DK_ + hi * 8;
    kq0[t] = gload16(kp_);
    kq1[t] = gload16(kp_ + 32);
  }
  int4 a00 = gload16(aw + ab0 + c0);
  int4 a01 = gload16(aw + ab0 + c0 + 4);
  int4 a02 = gload16(aw + ab0 + c0 + 512);
  int4 a03 = gload16(aw + ab0 + c0 + 516);
  // outstanding: 22.  oldest->newest: Q(2), K(16), awR0(4)

  VMW(20);  // Q ready
  const short8 qf0 = __builtin_bit_cast(short8, qd0);
  const short8 qf1 = __builtin_bit_cast(short8, qd1);

#define QK_EAT(t) do { \
    f32x4 sacc_ = (f32x4){0.f, 0.f, 0.f, 0.f}; \
    sacc_ = __builtin_amdgcn_mfma_f32_16x16x32_bf16(qf0, __builtin_bit_cast(short8, kq0[t]), sacc_, 0, 0, 0); \
    sacc_ = __builtin_amdgcn_mfma_f32_16x16x32_bf16(qf1, __builtin_bit_cast(short8, kq1[t]), sacc_, 0, 0, 0); \
    const int tk_ = (t) * 128 + tkc; \
    _Pragma("unroll") \
    for (int r = 0; r < 4; ++r) { \
      const int row_ = hi * 4 + r; \
      S[row_ * 1024 + (tk_ ^ ((row_ & 7) << 3))] = f2bf(sacc_[r]); \
    } } while (0)

  VMW(16);  QK_EAT(0); QK_EAT(1);
  VMW(12);  QK_EAT(2); QK_EAT(3);
  VMW(8);   QK_EAT(4); QK_EAT(5);
  VMW(4);   QK_EAT(6); QK_EAT(7);   // awR0(4) still in flight
#undef QK_EAT

  LGKM_BARRIER();   // S strip visible; aw loads NOT drained

  // ---- softmax (no max-sub): rows wave, wave+8 ----
  {
    const float scale = 0.125f;

#define SM_CONSUME(row_, bm_, A0_, A1_, A2_, A3_, ab_) do { \
    u16* Srow_ = S + (row_) * 1024; \
    const int swz_ = ((row_) & 7) << 3; \
    const short8 sL_ = ld_short8(Srow_ + (c0 ^ swz_)); \
    const short8 sH_ = ld_short8(Srow_ + ((c0 + 512) ^ swz_)); \
    const f32x4 awA_ = __builtin_bit_cast(f32x4, A0_); \
    const f32x4 awB_ = __builtin_bit_cast(f32x4, A1_); \
    const f32x4 awC_ = __builtin_bit_cast(f32x4, A2_); \
    const f32x4 awD_ = __builtin_bit_cast(f32x4, A3_); \
    f32x4 eA_, eB_, eC_, eD_; \
    _Pragma("unroll") \
    for (int jj = 0; jj < 4; ++jj) { \
      eA_[jj] = (((bm_) >> jj) & 1u) ? 0.f : __expf(bf2f((u16)sL_[jj]) * scale * awA_[jj]); \
      eB_[jj] = (((bm_) >> (4 + jj)) & 1u) ? 0.f : __expf(bf2f((u16)sL_[4 + jj]) * scale * awB_[jj]); \
      eC_[jj] = (((bm_) >> (8 + jj)) & 1u) ? 0.f : __expf(bf2f((u16)sH_[jj]) * scale * awC_[jj]); \
      eD_[jj] = (((bm_) >> (12 + jj)) & 1u) ? 0.f : __expf(bf2f((u16)sH_[4 + jj]) * scale * awD_[jj]); \
    } \
    float sum_ = 0.f; \
    _Pragma("unroll") \
    for (int jj = 0; jj < 4; ++jj) sum_ += (eA_[jj] + eB_[jj]) + (eC_[jj] + eD_[jj]); \
    _Pragma("unroll") \
    for (int o_ = 32; o_ >= 1; o_ >>= 1) sum_ += __shfl_xor(sum_, o_); \
    const float inv_ = 1.0f / sum_; \
    eA_ *= inv_; eB_ *= inv_; eC_ *= inv_; eD_ *= inv_; \
    *(f32x4*)(attout + (ab_) + c0) = eA_; \
    *(f32x4*)(attout + (ab_) + c0 + 4) = eB_; \
    *(f32x4*)(attout + (ab_) + c0 + 512) = eC_; \
    *(f32x4*)(attout + (ab_) + c0 + 516) = eD_; \
    short8 pL_, pH_; \
    _Pragma("unroll") \
    for (int jj = 0; jj < 4; ++jj) { \
      pL_[jj] = (short)f2bf(eA_[jj]); pL_[4 + jj] = (short)f2bf(eB_[jj]); \
      pH_[jj] = (short)f2bf(eC_[jj]); pH_[4 + jj] = (short)f2bf(eD_[jj]); \
    } \
    *(int4*)(Srow_ + (c0 ^ swz_)) = __builtin_bit_cast(int4, pL_); \
    *(int4*)(Srow_ + ((c0 + 512) ^ swz_)) = __builtin_bit_cast(int4, pH_); \
  } while (0)

    if (mflag) {
      const unsigned char* mp = (const unsigned char*)maskp;
      int2 s0a = gload8(mp + ab0 + c0);
      int2 s0b = gload8(mp + ab0 + c0 + 512);
      int2 d0a = gload8(mp + ab0 + c0);        // pad (uniform vmcnt count)
      int2 d0b = gload8(mp + ab0 + c0 + 512);  // pad
      int4 a10 = gload16(aw + ab1 + c0);
      int4 a11 = gload16(aw + ab1 + c0 + 4);
      int4 a12 = gload16(aw + ab1 + c0 + 512);
      int4 a13 = gload16(aw + ab1 + c0 + 516);
      int2 s1a = gload8(mp + ab1 + c0);
      int2 s1b = gload8(mp + ab1 + c0 + 512);
      int2 d1a = gload8(mp + ab1 + c0);        // pad
      int2 d1b = gload8(mp + ab1 + c0 + 512);  // pad
      (void)d0a; (void)d0b; (void)d1a; (void)d1b;
      VMW(8);  // awR0 + maskR0 ready; row1's 8 in flight
      u32 bm0 = 0;
#pragma unroll
      for (int j = 0; j < 4; ++j) {
        bm0 |= (((u32)s0a.x >> (8 * j)) & 1u) << j;
        bm0 |= (((u32)s0a.y >> (8 * j)) & 1u) << (4 + j);
        bm0 |= (((u32)s0b.x >> (8 * j)) & 1u) << (8 + j);
        bm0 |= (((u32)s0b.y >> (8 * j)) & 1u) << (12 + j);
      }
      SM_CONSUME(wave, bm0, a00, a01, a02, a03, ab0);
      VMW(4);  // row1 loads ready; row0 attout stores remain
      u32 bm1 = 0;
#pragma unroll
      for (int j = 0; j < 4; ++j) {
        bm1 |= (((u32)s1a.x >> (8 * j)) & 1u) << j;
        bm1 |= (((u32)s1a.y >> (8 * j)) & 1u) << (4 + j);
        bm1 |= (((u32)s1b.x >> (8 * j)) & 1u) << (8 + j);
        bm1 |= (((u32)s1b.y >> (8 * j)) & 1u) << (12 + j);
      }
      SM_CONSUME(wave + 8, bm1, a10, a11, a12, a13, ab1);
    } else {
      const int* mp = (const int*)maskp;
      int4 m00 = gload16(mp + ab0 + c0);
      int4 m01 = gload16(mp + ab0 + c0 + 4);
      int4 m02 = gload16(mp + ab0 + c0 + 512);
      int4 m03 = gload16(mp + ab0 + c0 + 516);
      int4 a10 = gload16(aw + ab1 + c0);
      int4 a11 = gload16(aw + ab1 + c0 + 4);
      int4 a12 = gload16(aw + ab1 + c0 + 512);
      int4 a13 = gload16(aw + ab1 + c0 + 516);
      int4 m10 = gload16(mp + ab1 + c0);
      int4 m11 = gload16(mp + ab1 + c0 + 4);
      int4 m12 = gload16(mp + ab1 + c0 + 512);
      int4 m13 = gload16(mp + ab1 + c0 + 516);
      VMW(8);  // awR0 + maskR0 ready
      u32 bm0 = ((u32)m00.x) | ((u32)m00.y << 1) | ((u32)m00.z << 2) | ((u32)m00.w << 3)
              | ((u32)m01.x << 4) | ((u32)m01.y << 5) | ((u32)m01.z << 6) | ((u32)m01.w << 7)
              | ((u32)m02.x << 8) | ((u32)m02.y << 9) | ((u32)m02.z << 10) | ((u32)m02.w << 11)
              | ((u32)m03.x << 12) | ((u32)m03.y << 13) | ((u32)m03.z << 14) | ((u32)m03.w << 15);
      SM_CONSUME(wave, bm0, a00, a01, a02, a03, ab0);
      VMW(4);  // row1 ready; row0 stores remain
      u32 bm1 = ((u32)m10.x) | ((u32)m10.y << 1) | ((u32)m10.z << 2) | ((u32)m10.w << 3)
              | ((u32)m11.x << 4) | ((u32)m11.y << 5) | ((u32)m11.z << 6) | ((u32)m11.w << 7)
              | ((u32)m12.x << 8) | ((u32)m12.y << 9) | ((u32)m12.z << 10) | ((u32)m12.w << 11)
              | ((u32)m13.x << 12) | ((u32)m13.y << 13) | ((u32)m13.z << 14) | ((u32)m13.w << 15);
      SM_CONSUME(wave + 8, bm1, a10, a11, a12, a13, ab1);
    }
#undef SM_CONSUME
  }

  LGKM_BARRIER();  // P strip visible for PV; attout stores still in flight
  VMW(0);          // clean FIFO before PV's counted pipeline

  // ---- PV: 2-way k-split, rolling asm vf pipeline, dual accumulators ----
  {
    const int kh = wave >> 2;
    const int j = wave & 3;
    const u16* Sr = S + l15 * 1024;
    const int asw = (l15 & 7) << 3;
    const int dcol = j * 16 + l15;
    const u16* vb = vTbuf + ((size_t)bh * DK_ + dcol) * (size_t)NK_;
    const int kh512 = kh * 512;
    f32x4 o0 = (f32x4){0.f, 0.f, 0.f, 0.f};
    f32x4 o1 = (f32x4){0.f, 0.f, 0.f, 0.f};
    int4 vq[16];

#define PV_ISSUE(t) do { vq[t] = gload16(vb + kh512 + (t) * 32 + hi * 8); } while (0)
#define PV_EAT(t) do { \
    const int c_ = kh512 + (t) * 32 + hi * 8; \
    const short8 pa_ = ld_short8(Sr + (c_ ^ asw)); \
    if ((t) & 1) o1 = __builtin_amdgcn_mfma_f32_16x16x32_bf16(pa_, __builtin_bit_cast(short8, vq[t]), o1, 0, 0, 0); \
    else        o0 = __builtin_amdgcn_mfma_f32_16x16x32_bf16(pa_, __builtin_bit_cast(short8, vq[t]), o0, 0, 0, 0); \
  } while (0)

    PV_ISSUE(0); PV_ISSUE(1); PV_ISSUE(2); PV_ISSUE(3);
    PV_ISSUE(4); PV_ISSUE(5); PV_ISSUE(6); PV_ISSUE(7);
    VMW(4);
    PV_EAT(0); PV_EAT(1); PV_EAT(2); PV_EAT(3);
    PV_ISSUE(8); PV_ISSUE(9); PV_ISSUE(10); PV_ISSUE(11);
    VMW(4);
    PV_EAT(4); PV_EAT(5); PV_EAT(6); PV_EAT(7);
    PV_ISSUE(12); PV_ISSUE(13); PV_ISSUE(14); PV_ISSUE(15);
    VMW(4);
    PV_EAT(8); PV_EAT(9); PV_EAT(10); PV_EAT(11);
    VMW(0);
    PV_EAT(12); PV_EAT(13); PV_EAT(14); PV_EAT(15);
#undef PV_ISSUE
#undef PV_EAT

    f32x4 oacc = o0 + o1;
    __syncthreads();                 // all P strip reads complete
    float* Pbuf = (float*)S;         // 16 x 64 fp32 partials (4 KB, aliases S)
    if (kh == 1) {
#pragma unroll
      for (int r = 0; r < 4; ++r)
        Pbuf[(hi * 4 + r) * 64 + dcol] = oacc[r];
    }
    __syncthreads();
    if (kh == 0) {
      const int feat = h * DK_ + dcol;
#pragma unroll
      for (int r = 0; r < 4; ++r) {
        const int row = hi * 4 + r;
        obuf[((size_t)b * NQ_ + qbase + row) * DM_ + feat] =
            f2bf(oacc[r] + Pbuf[row * 64 + dcol]);
      }
    }
  }
}

// ---------------------------------------------------------------------------
extern "C" void kernel_launch(void* const* d_in, const int* in_sizes, int n_in,
                              void* d_out, int out_size, void* d_ws, size_t ws_size,
                              hipStream_t stream)
{
  const float* queries = (const float*)d_in[0];
  const float* keys    = (const float*)d_in[1];
  const float* values  = (const float*)d_in[2];
  const float* aw      = (const float*)d_in[3];
  const void*  maskp   = d_in[4];
  const float* Wq = (const float*)d_in[5];
  const float* bq = (const float*)d_in[6];
  const float* Wk = (const float*)d_in[7];
  const float* bk = (const float*)d_in[8];
  const float* Wv = (const float*)d_in[9];
  const float* bv = (const float*)d_in[10];
  const float* Wo = (const float*)d_in[11];
  const float* bo = (const float*)d_in[12];

  char* ws = (char*)d_ws;
  const size_t NE = (size_t)B_ * H_ * NQ_ * DK_;  // 4,194,304
  int* flag  = (int*)ws;
  u16* qbuf  = (u16*)(ws + 256);
  u16* kbuf  = qbuf + NE;
  u16* vTbuf = kbuf + NE;
  u16* obuf  = vTbuf + NE;
  if (ws_size < 256 + 8 * NE) return;

  float* outp = (float*)d_out;
  float* attp = outp + (size_t)B_ * NQ_ * DM_;

  // bf16 scratch for converted q/k/v inputs lives in the att output region
  // (24 MB at the head of attp) -- fully consumed by the QKV GEMM, then
  // overwritten by attn.
  u16* cvt = (u16*)attp;
  const u16* cq = cvt;
  const u16* ck = cvt + NE;
  const u16* cv = cvt + 2 * NE;

  detect_mask_kernel<<<1, 64, 0, stream>>>((const unsigned char*)maskp, flag);

  convert_kernel<<<dim3(512, 3), 256, 0, stream>>>(queries, keys, values, cvt);

  gemm_kernel<<<dim3(8, 32, 3), 256, 0, stream>>>(cq, ck, cv, obuf,
      Wq, Wk, Wv, Wo, bq, bk, bv, bo, qbuf, kbuf, vTbuf, outp, 0);

  attn_kernel<<<dim3(4096), 512, 0, stream>>>(qbuf, kbuf, vTbuf, aw, maskp, flag,
                                              attp, obuf);

  gemm_kernel<<<dim3(8, 32, 1), 256, 0, stream>>>(cq, ck, cv, obuf,
      Wq, Wk, Wv, Wo, bq, bk, bv, bo, qbuf, kbuf, vTbuf, outp, 3);
}

// Round 11
// 321.104 us; speedup vs baseline: 1.1100x; 1.1100x over previous
//
#include <hip/hip_runtime.h>
#include <stdint.h>

#define B_ 4
#define H_ 16
#define NQ_ 1024
#define NK_ 1024
#define DM_ 1024
#define DK_ 64

typedef __attribute__((ext_vector_type(8))) short short8;
typedef __attribute__((ext_vector_type(4))) float f32x4;
typedef unsigned short u16;
typedef unsigned int u32;

__device__ __forceinline__ u16 f2bf(float f) {
  u32 u = __builtin_bit_cast(u32, f);
  u32 r = u + 0x7fffu + ((u >> 16) & 1u);
  return (u16)(r >> 16);
}

__device__ __forceinline__ float bf2f(u16 b) {
  u32 u = ((u32)b) << 16;
  return __builtin_bit_cast(float, u);
}

__device__ __forceinline__ short8 ld_short8(const u16* p) {
  return __builtin_bit_cast(short8, *(const int4*)p);
}

// ---- asm load primitives: volatile pins issue order; dests forced live ----
__device__ __forceinline__ int4 gload16(const void* p) {
  int4 d;
  asm volatile("global_load_dwordx4 %0, %1, off" : "=v"(d) : "v"(p));
  return d;
}
__device__ __forceinline__ int gload4(const void* p) {
  int d;
  asm volatile("global_load_dword %0, %1, off" : "=v"(d) : "v"(p));
  return d;
}
#define VMW(N) do { asm volatile("s_waitcnt vmcnt(" #N ")" ::: "memory"); \
                    __builtin_amdgcn_sched_barrier(0); } while (0)
#define LGKM_BARRIER() do { \
    asm volatile("s_waitcnt lgkmcnt(0)\n\ts_barrier" ::: "memory"); \
    __builtin_amdgcn_sched_barrier(0); } while (0)

// ---------------------------------------------------------------------------
// Mask storage detector: bool (1 byte/elem) vs int32 (4 bytes/elem).
// ---------------------------------------------------------------------------
__global__ void detect_mask_kernel(const unsigned char* __restrict__ m, int* __restrict__ flag) {
  if (threadIdx.x == 0) {
    int f = 0;
    for (int i = 0; i < 256; ++i)
      if ((i & 3) != 0 && m[i] != 0) f = 1;
    *flag = f;  // 1 => byte mask, 0 => int32 mask
  }
}

// ---------------------------------------------------------------------------
// GEMM (R9 version, fp32-A reg-staged): C = A W^T + bias.
// Only change: z==2 writes V in k-tiled layout vt2[bh][k/32][d][k%32] so
// attention PV loads are fully contiguous per instruction.
// ---------------------------------------------------------------------------
__global__ __launch_bounds__(256) void gemm_kernel(
    const float* __restrict__ Aq, const float* __restrict__ Ak, const float* __restrict__ Av,
    const u16* __restrict__ Ao,
    const float* __restrict__ Wq, const float* __restrict__ Wk,
    const float* __restrict__ Wv, const float* __restrict__ Wo,
    const float* __restrict__ bq, const float* __restrict__ bk,
    const float* __restrict__ bv, const float* __restrict__ bo,
    u16* __restrict__ qbuf, u16* __restrict__ kbuf, u16* __restrict__ vTbuf,
    float* __restrict__ outbuf, int mode_base)
{
  const int z = mode_base + (int)blockIdx.z;
  const int n0 = blockIdx.x * 128;
  const int m0 = blockIdx.y * 128;
  const int tid = threadIdx.x;
  const int lane = tid & 63;
  const int wave = tid >> 6;
  const int wm = wave >> 1, wn = wave & 1;

  __shared__ u16 Al[128 * 40];
  __shared__ u16 Bl[128 * 40];

  const float* Af = (z == 0) ? Aq : (z == 1 ? Ak : Av);
  const float* W  = (z == 0) ? Wq : (z == 1 ? Wk : (z == 2 ? Wv : Wo));

  f32x4 acc[4][4];
#pragma unroll
  for (int i = 0; i < 4; ++i)
#pragma unroll
    for (int j = 0; j < 4; ++j) acc[i][j] = (f32x4){0.f, 0.f, 0.f, 0.f};

  float4 arf[4];
  int4   arb[2];
  float4 brf[4];

  auto load_tiles = [&](int ks) {
    const int kk0 = ks * 32;
    if (z < 3) {
#pragma unroll
      for (int c = 0; c < 4; ++c) {
        int chunk = c * 256 + tid;
        arf[c] = *(const float4*)(Af + (size_t)(m0 + (chunk >> 3)) * DM_ + kk0 + (chunk & 7) * 4);
      }
    } else {
#pragma unroll
      for (int c = 0; c < 2; ++c) {
        int chunk = c * 256 + tid;
        arb[c] = *(const int4*)(Ao + (size_t)(m0 + (chunk >> 2)) * DM_ + kk0 + (chunk & 3) * 8);
      }
    }
#pragma unroll
    for (int c = 0; c < 4; ++c) {
      int chunk = c * 256 + tid;
      brf[c] = *(const float4*)(W + (size_t)(n0 + (chunk >> 3)) * DM_ + kk0 + (chunk & 7) * 4);
    }
  };

  auto store_lds = [&]() {
    if (z < 3) {
#pragma unroll
      for (int c = 0; c < 4; ++c) {
        int chunk = c * 256 + tid;
        ushort4 p;
        p.x = f2bf(arf[c].x); p.y = f2bf(arf[c].y); p.z = f2bf(arf[c].z); p.w = f2bf(arf[c].w);
        *(ushort4*)(Al + (chunk >> 3) * 40 + (chunk & 7) * 4) = p;
      }
    } else {
#pragma unroll
      for (int c = 0; c < 2; ++c) {
        int chunk = c * 256 + tid;
        *(int4*)(Al + (chunk >> 2) * 40 + (chunk & 3) * 8) = arb[c];
      }
    }
#pragma unroll
    for (int c = 0; c < 4; ++c) {
      int chunk = c * 256 + tid;
      ushort4 p;
      p.x = f2bf(brf[c].x); p.y = f2bf(brf[c].y); p.z = f2bf(brf[c].z); p.w = f2bf(brf[c].w);
      *(ushort4*)(Bl + (chunk >> 3) * 40 + (chunk & 7) * 4) = p;
    }
  };

  load_tiles(0);
  for (int ks = 0; ks < 32; ++ks) {
    __syncthreads();
    store_lds();
    __syncthreads();
    if (ks < 31) load_tiles(ks + 1);
    short8 afr[4], bfr[4];
#pragma unroll
    for (int i = 0; i < 4; ++i) {
      afr[i] = ld_short8(Al + (wm * 64 + i * 16 + (lane & 15)) * 40 + (lane >> 4) * 8);
      bfr[i] = ld_short8(Bl + (wn * 64 + i * 16 + (lane & 15)) * 40 + (lane >> 4) * 8);
    }
#pragma unroll
    for (int i = 0; i < 4; ++i)
#pragma unroll
      for (int j = 0; j < 4; ++j)
        acc[i][j] = __builtin_amdgcn_mfma_f32_16x16x32_bf16(afr[i], bfr[j], acc[i][j], 0, 0, 0);
  }

  const float* bias = (z == 0) ? bq : (z == 1 ? bk : (z == 2 ? bv : bo));
#pragma unroll
  for (int i = 0; i < 4; ++i) {
    const int token0 = m0 + wm * 64 + i * 16 + (lane >> 4) * 4;
#pragma unroll
    for (int j = 0; j < 4; ++j) {
      const int feat = n0 + wn * 64 + j * 16 + (lane & 15);
      const float bvl = bias[feat];
      if (z == 3) {
#pragma unroll
        for (int r = 0; r < 4; ++r)
          outbuf[(size_t)(token0 + r) * DM_ + feat] = acc[i][j][r] + bvl;
      } else if (z == 2) {
        // V k-tiled: vt2[bh][k/32][d][k%32]
        const int bb = token0 >> 10, t = token0 & 1023;
        const int hh = feat >> 6, d = feat & 63;
        const int kt = t >> 5, kk = t & 31;
        ushort4 p;
        p.x = f2bf(acc[i][j][0] + bvl);
        p.y = f2bf(acc[i][j][1] + bvl);
        p.z = f2bf(acc[i][j][2] + bvl);
        p.w = f2bf(acc[i][j][3] + bvl);
        *(ushort4*)(vTbuf + (((size_t)(bb * H_ + hh) * 32 + kt) * 64 + d) * 32 + kk) = p;
      } else {
        u16* dst = (z == 0) ? qbuf : kbuf;
        const int hh = feat >> 6, d = feat & 63;
#pragma unroll
        for (int r = 0; r < 4; ++r) {
          const int token = token0 + r;
          const int bb = token >> 10, t = token & 1023;
          dst[((size_t)(bb * H_ + hh) * NQ_ + t) * DK_ + d] = f2bf(acc[i][j][r] + bvl);
        }
      }
    }
  }
}

// ---------------------------------------------------------------------------
// Attention v10: R9 skeleton + fully-contiguous per-instruction global access.
// Softmax: lane owns cols {lane*4 + j*256} -> every aw/attout instruction
// tiles 1 KB contiguous; mask via dword loads. PV: V in k-tiled layout ->
// each vq gload16 tiles 4 KB contiguous (16 lines vs 64).
// ---------------------------------------------------------------------------
__global__ __launch_bounds__(512) void attn_kernel(
    const u16* __restrict__ qbuf, const u16* __restrict__ kbuf, const u16* __restrict__ vTbuf,
    const float* __restrict__ aw, const void* __restrict__ maskp, const int* __restrict__ flagp,
    float* __restrict__ attout, u16* __restrict__ obuf)
{
  __shared__ u16 S[16 * 1024];  // 32 KB bf16 strip, col swizzle: c ^ ((row&7)<<3)

  const int n = blockIdx.x;
  const int work = (n & 7) * 512 + (n >> 3);  // XCD-chunked swizzle (perf only)
  const int qt = work & 63;
  const int bh = work >> 6;
  const int b = bh >> 4, h = bh & 15;
  const int qbase = qt * 16;
  const int tid = threadIdx.x;
  const int lane = tid & 63;
  const int wave = tid >> 6;   // 0..7
  const int hi = lane >> 4;
  const int l15 = lane & 15;
  const int l4 = lane * 4;
  const int mflag = *flagp;

  const size_t ab0 = ((size_t)bh * NQ_ + qbase + wave) * (size_t)NK_;
  const size_t ab1 = ab0 + 8 * (size_t)NK_;

  // ---- pre-QK issue: Q(2), K(16), aw row0(4) -- FIFO order is the contract
  const u16* qp = qbuf + ((size_t)bh * NQ_ + qbase + l15) * DK_ + hi * 8;
  int4 qd0 = gload16(qp);
  int4 qd1 = gload16(qp + 32);

  const u16* kbase = kbuf + (size_t)bh * NK_ * DK_;
  const int tkc = wave * 16 + l15;
  int4 kq0[8], kq1[8];
#pragma unroll
  for (int t = 0; t < 8; ++t) {
    const u16* kp_ = kbase + (size_t)(t * 128 + tkc) * DK_ + hi * 8;
    kq0[t] = gload16(kp_);
    kq1[t] = gload16(kp_ + 32);
  }
  int4 aw0[4];
#pragma unroll
  for (int j = 0; j < 4; ++j) aw0[j] = gload16(aw + ab0 + l4 + j * 256);
  // outstanding: 22.  oldest->newest: Q(2), K(16), awR0(4)

  VMW(20);  // Q ready
  const short8 qf0 = __builtin_bit_cast(short8, qd0);
  const short8 qf1 = __builtin_bit_cast(short8, qd1);

#define QK_EAT(t) do { \
    f32x4 sacc_ = (f32x4){0.f, 0.f, 0.f, 0.f}; \
    sacc_ = __builtin_amdgcn_mfma_f32_16x16x32_bf16(qf0, __builtin_bit_cast(short8, kq0[t]), sacc_, 0, 0, 0); \
    sacc_ = __builtin_amdgcn_mfma_f32_16x16x32_bf16(qf1, __builtin_bit_cast(short8, kq1[t]), sacc_, 0, 0, 0); \
    const int tk_ = (t) * 128 + tkc; \
    _Pragma("unroll") \
    for (int r = 0; r < 4; ++r) { \
      const int row_ = hi * 4 + r; \
      S[row_ * 1024 + (tk_ ^ ((row_ & 7) << 3))] = f2bf(sacc_[r]); \
    } } while (0)

  VMW(16);  QK_EAT(0); QK_EAT(1);
  VMW(12);  QK_EAT(2); QK_EAT(3);
  VMW(8);   QK_EAT(4); QK_EAT(5);
  VMW(4);   QK_EAT(6); QK_EAT(7);   // awR0(4) still in flight
#undef QK_EAT

  LGKM_BARRIER();   // S strip visible; aw loads NOT drained

  // ---- softmax (no max-sub): rows wave, wave+8; contiguous access ----
  {
    const float scale = 0.125f;

// K0_..K3_ are int4 mask flags (nonzero => masked out)
#define SM_BODY(row_, AWV_, KV_, ab_) do { \
    u16* Srow_ = S + (row_) * 1024; \
    const int swz_ = ((row_) & 7) << 3; \
    f32x4 e_[4]; float sum_ = 0.f; \
    _Pragma("unroll") \
    for (int j = 0; j < 4; ++j) { \
      const int c_ = l4 + j * 256; \
      const ushort4 s4_ = *(const ushort4*)(Srow_ + (c_ ^ swz_)); \
      const f32x4 a4_ = __builtin_bit_cast(f32x4, AWV_[j]); \
      f32x4 t_; \
      t_[0] = KV_[j].x ? 0.f : __expf(bf2f(s4_.x) * scale * a4_[0]); \
      t_[1] = KV_[j].y ? 0.f : __expf(bf2f(s4_.y) * scale * a4_[1]); \
      t_[2] = KV_[j].z ? 0.f : __expf(bf2f(s4_.z) * scale * a4_[2]); \
      t_[3] = KV_[j].w ? 0.f : __expf(bf2f(s4_.w) * scale * a4_[3]); \
      e_[j] = t_; \
      sum_ += (t_[0] + t_[1]) + (t_[2] + t_[3]); \
    } \
    _Pragma("unroll") \
    for (int o_ = 32; o_ >= 1; o_ >>= 1) sum_ += __shfl_xor(sum_, o_); \
    const float inv_ = 1.0f / sum_; \
    _Pragma("unroll") \
    for (int j = 0; j < 4; ++j) { \
      const int c_ = l4 + j * 256; \
      f32x4 t_ = e_[j]; \
      t_[0] *= inv_; t_[1] *= inv_; t_[2] *= inv_; t_[3] *= inv_; \
      *(f32x4*)(attout + (ab_) + c_) = t_; \
      ushort4 p_; \
      p_.x = f2bf(t_[0]); p_.y = f2bf(t_[1]); p_.z = f2bf(t_[2]); p_.w = f2bf(t_[3]); \
      *(ushort4*)(Srow_ + (c_ ^ swz_)) = p_; \
    } \
  } while (0)

    if (mflag) {
      const unsigned char* mp = (const unsigned char*)maskp;
      int mb0[4], mb1[4];
      int4 aw1[4];
#pragma unroll
      for (int j = 0; j < 4; ++j) mb0[j] = gload4(mp + ab0 + l4 + j * 256);
#pragma unroll
      for (int j = 0; j < 4; ++j) aw1[j] = gload16(aw + ab1 + l4 + j * 256);
#pragma unroll
      for (int j = 0; j < 4; ++j) mb1[j] = gload4(mp + ab1 + l4 + j * 256);
      VMW(8);  // awR0 + maskR0 ready; row1's 8 in flight
      int4 k0[4], k1[4];
#pragma unroll
      for (int j = 0; j < 4; ++j) {
        k0[j].x = mb0[j] & 0xff;          k0[j].y = (mb0[j] >> 8) & 0xff;
        k0[j].z = (mb0[j] >> 16) & 0xff;  k0[j].w = (mb0[j] >> 24) & 0xff;
      }
      SM_BODY(wave, aw0, k0, ab0);
      VMW(4);  // awR1 + maskR1 ready; row0's 4 attout stores remain
#pragma unroll
      for (int j = 0; j < 4; ++j) {
        k1[j].x = mb1[j] & 0xff;          k1[j].y = (mb1[j] >> 8) & 0xff;
        k1[j].z = (mb1[j] >> 16) & 0xff;  k1[j].w = (mb1[j] >> 24) & 0xff;
      }
      SM_BODY(wave + 8, aw1, k1, ab1);
    } else {
      const int* mp = (const int*)maskp;
      int4 k0[4], aw1[4], k1[4];
#pragma unroll
      for (int j = 0; j < 4; ++j) k0[j] = gload16(mp + ab0 + l4 + j * 256);
#pragma unroll
      for (int j = 0; j < 4; ++j) aw1[j] = gload16(aw + ab1 + l4 + j * 256);
#pragma unroll
      for (int j = 0; j < 4; ++j) k1[j] = gload16(mp + ab1 + l4 + j * 256);
      VMW(8);  // awR0 + maskR0 ready
      SM_BODY(wave, aw0, k0, ab0);
      VMW(4);  // row1 loads ready; row0 stores remain
      SM_BODY(wave + 8, aw1, k1, ab1);
    }
#undef SM_BODY
  }

  LGKM_BARRIER();  // P strip visible for PV; attout stores still in flight
  VMW(0);          // clean FIFO before PV's counted pipeline

  // ---- PV: 2-way k-split, k-tiled V (contiguous loads), dual accumulators
  {
    const int kh = wave >> 2;
    const int j = wave & 3;
    const u16* Sr = S + l15 * 1024;
    const int asw = (l15 & 7) << 3;
    const int dcol = j * 16 + l15;
    const u16* vb2 = vTbuf + (size_t)bh * (NK_ * DK_);
    const int kh512 = kh * 512;
    f32x4 o0 = (f32x4){0.f, 0.f, 0.f, 0.f};
    f32x4 o1 = (f32x4){0.f, 0.f, 0.f, 0.f};
    int4 vq[16];

#define PV_ISSUE(t) do { \
    vq[t] = gload16(vb2 + ((size_t)(kh * 16 + (t)) * 64 + dcol) * 32 + hi * 8); } while (0)
#define PV_EAT(t) do { \
    const int c_ = kh512 + (t) * 32 + hi * 8; \
    const short8 pa_ = ld_short8(Sr + (c_ ^ asw)); \
    if ((t) & 1) o1 = __builtin_amdgcn_mfma_f32_16x16x32_bf16(pa_, __builtin_bit_cast(short8, vq[t]), o1, 0, 0, 0); \
    else        o0 = __builtin_amdgcn_mfma_f32_16x16x32_bf16(pa_, __builtin_bit_cast(short8, vq[t]), o0, 0, 0, 0); \
  } while (0)

    PV_ISSUE(0); PV_ISSUE(1); PV_ISSUE(2); PV_ISSUE(3);
    PV_ISSUE(4); PV_ISSUE(5); PV_ISSUE(6); PV_ISSUE(7);
    VMW(4);
    PV_EAT(0); PV_EAT(1); PV_EAT(2); PV_EAT(3);
    PV_ISSUE(8); PV_ISSUE(9); PV_ISSUE(10); PV_ISSUE(11);
    VMW(4);
    PV_EAT(4); PV_EAT(5); PV_EAT(6); PV_EAT(7);
    PV_ISSUE(12); PV_ISSUE(13); PV_ISSUE(14); PV_ISSUE(15);
    VMW(4);
    PV_EAT(8); PV_EAT(9); PV_EAT(10); PV_EAT(11);
    VMW(0);
    PV_EAT(12); PV_EAT(13); PV_EAT(14); PV_EAT(15);
#undef PV_ISSUE
#undef PV_EAT

    f32x4 oacc = o0 + o1;
    __syncthreads();                 // all P strip reads complete
    float* Pbuf = (float*)S;         // 16 x 64 fp32 partials (4 KB, aliases S)
    if (kh == 1) {
#pragma unroll
      for (int r = 0; r < 4; ++r)
        Pbuf[(hi * 4 + r) * 64 + dcol] = oacc[r];
    }
    __syncthreads();
    if (kh == 0) {
      const int feat = h * DK_ + dcol;
#pragma unroll
      for (int r = 0; r < 4; ++r) {
        const int row = hi * 4 + r;
        obuf[((size_t)b * NQ_ + qbase + row) * DM_ + feat] =
            f2bf(oacc[r] + Pbuf[row * 64 + dcol]);
      }
    }
  }
}

// ---------------------------------------------------------------------------
extern "C" void kernel_launch(void* const* d_in, const int* in_sizes, int n_in,
                              void* d_out, int out_size, void* d_ws, size_t ws_size,
                              hipStream_t stream)
{
  const float* queries = (const float*)d_in[0];
  const float* keys    = (const float*)d_in[1];
  const float* values  = (const float*)d_in[2];
  const float* aw      = (const float*)d_in[3];
  const void*  maskp   = d_in[4];
  const float* Wq = (const float*)d_in[5];
  const float* bq = (const float*)d_in[6];
  const float* Wk = (const float*)d_in[7];
  const float* bk = (const float*)d_in[8];
  const float* Wv = (const float*)d_in[9];
  const float* bv = (const float*)d_in[10];
  const float* Wo = (const float*)d_in[11];
  const float* bo = (const float*)d_in[12];

  char* ws = (char*)d_ws;
  const size_t NE = (size_t)B_ * H_ * NQ_ * DK_;
  int* flag  = (int*)ws;
  u16* qbuf  = (u16*)(ws + 256);
  u16* kbuf  = qbuf + NE;
  u16* vTbuf = kbuf + NE;
  u16* obuf  = vTbuf + NE;
  if (ws_size < 256 + 8 * NE) return;

  float* outp = (float*)d_out;
  float* attp = outp + (size_t)B_ * NQ_ * DM_;

  detect_mask_kernel<<<1, 64, 0, stream>>>((const unsigned char*)maskp, flag);

  gemm_kernel<<<dim3(8, 32, 3), 256, 0, stream>>>(queries, keys, values, obuf,
      Wq, Wk, Wv, Wo, bq, bk, bv, bo, qbuf, kbuf, vTbuf, outp, 0);

  attn_kernel<<<dim3(4096), 512, 0, stream>>>(qbuf, kbuf, vTbuf, aw, maskp, flag,
                                              attp, obuf);

  gemm_kernel<<<dim3(8, 32, 1), 256, 0, stream>>>(queries, keys, values, obuf,
      Wq, Wk, Wv, Wo, bq, bk, bv, bo, qbuf, kbuf, vTbuf, outp, 3);
}